// Round 23
// baseline (417.109 us; speedup 1.0000x reference)
//
#include <hip/hip_runtime.h>
#include <hip/hip_bf16.h>

#define NCODES 8192
#define CDIM 128
#define NTOT (16*128*32*32)   // 2097152
#define KTOT 22272            // sum of 256-aligned per-level keys regions

typedef __attribute__((ext_vector_type(8))) short bf16x8;
typedef __attribute__((ext_vector_type(16))) float f32x16;
typedef unsigned long long u64;
typedef unsigned int u32;
typedef unsigned short ushort_t;

__device__ __forceinline__ ushort_t f2bf(float x) {
    u32 u = __float_as_uint(x);
    u32 r = (u + 0x7FFFu + ((u >> 16) & 1u)) >> 16;
    return (ushort_t)r;
}
__device__ __forceinline__ float bf2f(ushort_t h) {
    return __uint_as_float(((u32)h) << 16);
}
__device__ __forceinline__ void gload_lds16(const void* g, void* l) {
    __builtin_amdgcn_global_load_lds(
        (const __attribute__((address_space(1))) unsigned int*)g,
        (__attribute__((address_space(3))) unsigned int*)l, 16, 0, 0);
}

// ---------------- init: emb pack+esq (bid<256) || keys init + lvl0 down -------
__global__ __launch_bounds__(256) void init_kernel(const float* __restrict__ emb,
        const float* __restrict__ z_enc, ushort_t* __restrict__ emb_pk,
        float* __restrict__ esq, float* __restrict__ zd, u64* __restrict__ keys) {
    int bid = blockIdx.x, t = threadIdx.x;
    if (bid < 256) {   // ---- emb pack + esq ----
        __shared__ float sm[32][129];
        int rb = bid;
        int rl = t >> 3, d0 = (t & 7) * 16;
        const float4* s4 = (const float4*)(emb + (size_t)(rb * 32 + rl) * CDIM + d0);
        #pragma unroll
        for (int j = 0; j < 4; j++) {
            float4 v = s4[j];
            sm[rl][d0 + 4*j + 0] = v.x; sm[rl][d0 + 4*j + 1] = v.y;
            sm[rl][d0 + 4*j + 2] = v.z; sm[rl][d0 + 4*j + 3] = v.w;
        }
        __syncthreads();
        {   // esq: 8 threads per code row, 16 dims each
            int r = t >> 3, g = t & 7;
            float s = 0.f;
            #pragma unroll
            for (int k = 0; k < 16; k++) { float x = sm[r][g * 16 + k]; s += x * x; }
            s += __shfl_xor(s, 1, 64);
            s += __shfl_xor(s, 2, 64);
            s += __shfl_xor(s, 4, 64);
            if (g == 0) esq[rb * 32 + r] = s;
        }
        #pragma unroll
        for (int k = 0; k < 2; k++) {
            int s = t + 256 * k;
            int c = s >> 6, l = s & 63;
            int r = l & 31, dbase = c * 16 + (l >> 5) * 8;
            bf16x8 vh, vl;
            #pragma unroll
            for (int e = 0; e < 8; e++) {
                float x = sm[r][dbase + e];
                ushort_t hh = f2bf(x);
                vh[e] = (short)hh;
                vl[e] = (short)f2bf(x - bf2f(hh));
            }
            size_t base = ((size_t)(rb * 8 + c) * 2) * 512 + (size_t)l * 8;
            *(bf16x8*)(emb_pk + base)       = vh;
            *(bf16x8*)(emb_pk + base + 512) = vl;
        }
    } else {           // ---- keys init + lvl0 area downsample ----
        int gi = (bid - 256) * 256 + t;
        if (gi < KTOT) keys[gi] = ~0ull;
        int item = gi >> 6;
        int wi   = gi & 63;
        int row = item >> 7, dim = item & 127;   // row in [0,16)
        const float* sp = z_enc + (((size_t)row * CDIM + dim) * 32) * 32;
        float s = 0.f;
        #pragma unroll
        for (int k = 0; k < 16; k++) {
            int flat = wi * 16 + k;
            s += sp[(flat >> 5) * 32 + (flat & 31)];
        }
        #pragma unroll
        for (int d = 32; d; d >>= 1) s += __shfl_xor(s, d, 64);
        if (wi == 0) zd[(size_t)row * CDIM + dim] = s * (1.0f / 1024.0f);
    }
}

// ---------------- MFMA argmin (fused A-pack): 8 waves x 32 rows --------------
// cstep = min(cps, 128) codes per barrier step (2x64KB LDS double buffer,
// 136KB total). Per step: ngr/2 pair-iterations of the proven 2-chain body;
// only 2 accs live at a time -> ~84 VGPR, no spill. Halves the ~1800cyc fixed
// per-step cost per code vs C=64 (validated lever: R11 C=32->64 gave -22%).
__global__ __launch_bounds__(512) void argmin_kernel(
        const float* __restrict__ zsrc, const ushort_t* __restrict__ bpk,
        const float* __restrict__ esq, u64* __restrict__ keys,
        int tiles, int slices, int nrows, int bchw) {
    __shared__ ushort_t lds[2][32768];   // 2 x 64 KB
    __shared__ float es_lds[2048];

    int cps   = NCODES / slices;
    int cstep = cps < 128 ? cps : 128;   // 64 or 128
    int ngr   = cstep >> 5;              // 2 or 4 groups of 32 codes
    int steps = cps / cstep;
    int stepB = cstep << 9;              // bytes per step block
    int bid = blockIdx.x;
    int tile  = bid / slices;
    int slice = bid % slices;
    int code0 = slice * cps;
    int tid = threadIdx.x, wv = tid >> 6, l = tid & 63, l31 = l & 31, lh = l >> 5;

    // A fragments (32 rows/wave): load f32, scale -2, hi/lo split in regs
    int rb = tile * 8 + wv;
    bf16x8 a_h[8], a_l[8];
    if (bchw) {
        int b = rb >> 5, h = rb & 31;
        const float* zr = zsrc + (size_t)b * 131072 + h * 32 + l31;
        #pragma unroll
        for (int c = 0; c < 8; c++) {
            #pragma unroll
            for (int e = 0; e < 8; e++) {
                int d = c * 16 + lh * 8 + e;
                float x = -2.0f * zr[(size_t)d * 1024];
                ushort_t hh = f2bf(x);
                a_h[c][e] = (short)hh;
                a_l[c][e] = (short)f2bf(x - bf2f(hh));
            }
        }
    } else {
        int row = rb * 32 + l31;
        if (row > nrows - 1) row = nrows - 1;
        const float* zr = zsrc + (size_t)row * CDIM + lh * 8;
        #pragma unroll
        for (int c = 0; c < 8; c++) {
            float4 f0 = *(const float4*)(zr + c * 16);
            float4 f1 = *(const float4*)(zr + c * 16 + 4);
            float xs[8] = {f0.x, f0.y, f0.z, f0.w, f1.x, f1.y, f1.z, f1.w};
            #pragma unroll
            for (int e = 0; e < 8; e++) {
                float x = -2.0f * xs[e];
                ushort_t hh = f2bf(x);
                a_h[c][e] = (short)hh;
                a_l[c][e] = (short)f2bf(x - bf2f(hh));
            }
        }
    }
    float ev0 = 0.f, ev1 = 0.f, ev2 = 0.f, ev3 = 0.f;
    if (tid < cps)        ev0 = esq[code0 + tid];
    if (512  + tid < cps) ev1 = esq[code0 + 512 + tid];
    if (1024 + tid < cps) ev2 = esq[code0 + 1024 + tid];
    if (1536 + tid < cps) ev3 = esq[code0 + 1536 + tid];
    __builtin_amdgcn_sched_barrier(0);   // pin: A+esq before staging

    const char* bbase = (const char*)bpk + (size_t)code0 * 512;
    int wb = wv * ngr * 2048;            // this wave's byte offset in a step block
    {   // prologue: stage step 0 into buf 0 (2*ngr x 1KB per wave)
        const char* g0 = bbase + (size_t)wb + (size_t)l * 16;
        ushort_t* d0 = &lds[0][wb >> 1];
        for (int q = 0; q < 2 * ngr; q++)
            gload_lds16(g0 + q * 1024, d0 + q * 512);
    }
    __builtin_amdgcn_sched_barrier(0);
    if (tid < cps)        es_lds[tid] = ev0;
    if (512  + tid < cps) es_lds[512 + tid] = ev1;
    if (1024 + tid < cps) es_lds[1024 + tid] = ev2;
    if (1536 + tid < cps) es_lds[1536 + tid] = ev3;
    asm volatile("s_waitcnt lgkmcnt(0)" ::: "memory");

    float best[16];
    int   bidx[16];
    #pragma unroll
    for (int r = 0; r < 16; r++) { best[r] = 1e38f; bidx[r] = 0; }

    for (int t = 0; t < steps; ++t) {
        asm volatile("s_waitcnt vmcnt(0)" ::: "memory");  // own stage(t) landed
        __builtin_amdgcn_s_barrier();    // buf[t&1] staged; buf[(t+1)&1] free
        if (t + 1 < steps) {             // stage t+1
            const char* g = bbase + (size_t)(t + 1) * stepB
                          + (size_t)wb + (size_t)l * 16;
            ushort_t* d = &lds[(t + 1) & 1][wb >> 1];
            for (int q = 0; q < 2 * ngr; q++)
                gload_lds16(g + q * 1024, d + q * 512);
        }
        const ushort_t* lpb = &lds[t & 1][0] + l * 8;
        __builtin_amdgcn_s_setprio(1);
        for (int gp = 0; gp < (ngr >> 1); gp++) {
            float es0 = es_lds[t * cstep + (gp << 6) + l31];
            float es1 = es_lds[t * cstep + (gp << 6) + 32 + l31];
            f32x16 acc0, acc1;
            #pragma unroll
            for (int r = 0; r < 16; r++) { acc0[r] = es0; acc1[r] = es1; }
            const ushort_t* lp = lpb + gp * 16384;
            #pragma unroll
            for (int c = 0; c < 8; c++) {
                bf16x8 g0h = *(const bf16x8*)(lp + (2 * c) * 512);
                bf16x8 g0l = *(const bf16x8*)(lp + (2 * c + 1) * 512);
                bf16x8 g1h = *(const bf16x8*)(lp + 8192 + (2 * c) * 512);
                bf16x8 g1l = *(const bf16x8*)(lp + 8192 + (2 * c + 1) * 512);
                acc0 = __builtin_amdgcn_mfma_f32_32x32x16_bf16(a_h[c], g0h, acc0, 0, 0, 0);
                acc1 = __builtin_amdgcn_mfma_f32_32x32x16_bf16(a_h[c], g1h, acc1, 0, 0, 0);
                acc0 = __builtin_amdgcn_mfma_f32_32x32x16_bf16(a_h[c], g0l, acc0, 0, 0, 0);
                acc1 = __builtin_amdgcn_mfma_f32_32x32x16_bf16(a_h[c], g1l, acc1, 0, 0, 0);
                acc0 = __builtin_amdgcn_mfma_f32_32x32x16_bf16(a_l[c], g0h, acc0, 0, 0, 0);
                acc1 = __builtin_amdgcn_mfma_f32_32x32x16_bf16(a_l[c], g1h, acc1, 0, 0, 0);
            }
            int code = code0 + t * cstep + (gp << 6) + l31;
            #pragma unroll
            for (int r = 0; r < 16; r++) {
                float s0 = acc0[r], s1 = acc1[r];
                float m  = fminf(s0, s1);
                int   ci = (s0 <= s1) ? code : code + 32;   // tie -> lower index
                bool lt = m < best[r];
                best[r] = lt ? m : best[r];
                bidx[r] = lt ? ci : bidx[r];
            }
        }
        __builtin_amdgcn_s_setprio(0);
    }

    #pragma unroll
    for (int r = 0; r < 16; r++) {
        u32 fb = __float_as_uint(best[r]);
        fb = (fb & 0x80000000u) ? ~fb : (fb | 0x80000000u);
        u64 key = ((u64)fb << 32) | (u32)bidx[r];
        #pragma unroll
        for (int d = 1; d < 32; d <<= 1) {
            u64 o = __shfl_xor(key, d, 64);
            key = (o < key) ? o : key;
        }
        if (l31 == 0) {
            int rw = tile * 256 + wv * 32 + (r & 3) + 8 * (r >> 2) + 4 * lh;
            atomicMin(&keys[rw], key);
        }
    }
}

// ---------------- bicubic weight (a = -0.75) ----------------
__device__ __forceinline__ float cubicw(float t) {
    float t2 = t * t;
    if (t <= 1.0f) return (1.25f * t - 2.25f) * t2 + 1.0f;
    return -0.75f * (((t - 5.0f) * t + 8.0f) * t - 4.0f);
}

// ---------------- upsample + residual update + output + FUSED downsample ----------
__global__ __launch_bounds__(256) void up_kernel(
        const float* __restrict__ emb,
        const u64* __restrict__ keys,
        const float* __restrict__ src,   // z_enc (lvl0) or zrest
        const float* __restrict__ prev,  // out[lvl-1] (unused if first)
        float* __restrict__ zrest,
        float* __restrict__ out,
        float* __restrict__ zd_next,     // next level's zd (if pnn > 0)
        int pn, int last, int first, int pnn) {
    __shared__ float wtab[32][4];
    __shared__ int   itab[32][4];
    __shared__ float smp[512];
    int tid = threadIdx.x;
    if (!last && tid < 128) {
        int pos = tid >> 2, tap = tid & 3;
        float s  = (float)pn * (1.0f / 32.0f);
        float x  = ((float)pos + 0.5f) * s - 0.5f;
        float x0 = floorf(x);
        float t  = x - x0;
        int   off = tap - 1;
        float w  = cubicw(fabsf((float)off - t));
        int   jj = (int)x0 + off;
        jj = min(max(jj, 0), pn - 1);
        wtab[pos][tap] = w;
        itab[pos][tap] = jj;
    }
    __syncthreads();

    int t  = blockIdx.x * 256 + tid;
    int w4 = (t & 7) << 2;
    int h  = (t >> 3) & 31;
    int c  = (t >> 8) & 127;
    int b  = t >> 15;
    size_t i = (((size_t)b * CDIM + c) * 32 + h) * 32 + w4;

    float zu[4];
    if (last) {
        int kb = (b << 10) + (h << 5) + w4;
        #pragma unroll
        for (int j = 0; j < 4; j++) {
            int tok = (int)(keys[kb + j] & 0xFFFFFFFFull);
            zu[j] = emb[(size_t)tok * CDIM + c];
        }
    } else {
        int base = b * pn * pn;
        #pragma unroll
        for (int j = 0; j < 4; j++) zu[j] = 0.f;
        #pragma unroll
        for (int u = 0; u < 4; u++) {
            float whu = wtab[h][u];
            int   ih  = itab[h][u] * pn;
            #pragma unroll
            for (int j = 0; j < 4; j++) {
                float acc = 0.f;
                #pragma unroll
                for (int v = 0; v < 4; v++) {
                    int tok = (int)(keys[base + ih + itab[w4 + j][v]] & 0xFFFFFFFFull);
                    acc += wtab[w4 + j][v] * emb[(size_t)tok * CDIM + c];
                }
                zu[j] += whu * acc;
            }
        }
    }
    float4 sv = *(const float4*)(src + i);
    float4 pv = {0.f, 0.f, 0.f, 0.f};
    if (!first) pv = *(const float4*)(prev + i);
    float4 ov, rv;
    ov.x = pv.x + zu[0]; ov.y = pv.y + zu[1]; ov.z = pv.z + zu[2]; ov.w = pv.w + zu[3];
    rv.x = sv.x - zu[0]; rv.y = sv.y - zu[1]; rv.z = sv.z - zu[2]; rv.w = sv.w - zu[3];
    *(float4*)(out + i)   = ov;
    *(float4*)(zrest + i) = rv;

    if (pnn) {   // fused area-downsample of rv for next level
        int f = 32 / pnn;
        if (f >= 4) {
            smp[h * 8 + (w4 >> 2)] = (rv.x + rv.y) + (rv.z + rv.w);
        } else {  // f == 2
            smp[h * 16 + (w4 >> 1)]     = rv.x + rv.y;
            smp[h * 16 + (w4 >> 1) + 1] = rv.z + rv.w;
        }
        __syncthreads();
        int W = pnn * pnn;
        if (tid < W) {
            int lb = __builtin_ctz(pnn);
            int ph = tid >> lb, pw = tid & (pnn - 1);
            float s = 0.f;
            if (f >= 4) {
                int cg = f >> 2;
                for (int u = 0; u < f; u++)
                    for (int v = 0; v < cg; v++)
                        s += smp[(ph * f + u) * 8 + pw * cg + v];
            } else {
                s = smp[(2 * ph) * 16 + pw] + smp[(2 * ph + 1) * 16 + pw];
            }
            int b2 = blockIdx.x >> 7, c2 = blockIdx.x & 127;
            int row = (b2 * pnn + ph) * pnn + pw;
            zd_next[(size_t)row * CDIM + c2] = s * (1.0f / (float)(f * f));
        }
    }
}

extern "C" void kernel_launch(void* const* d_in, const int* in_sizes, int n_in,
                              void* d_out, int out_size, void* d_ws, size_t ws_size,
                              hipStream_t stream) {
    const float* z_enc = (const float*)d_in[0];
    const float* emb   = (const float*)d_in[1];
    float* out = (float*)d_out;
    float* ws  = (float*)d_ws;

    // ws layout (float offsets)
    float*    zrest  = ws;                                // 2,097,152
    float*    zd_f32 = ws + 2097152;                      // 2,097,152
    ushort_t* emb_pk = (ushort_t*)(ws + 4194304);         // 2,097,152 ushort
    float*    esq    = ws + 5242880;                      // 8192
    u64*      keys   = (u64*)(ws + 5251072);              // KTOT u64

    init_kernel<<<768, 256, 0, stream>>>(emb, z_enc, emb_pk, esq, zd_f32, keys);

    const int MS_[6]   = {1, 2, 4, 8, 16, 32};
    const int SL_[6]   = {128, 128, 128, 64, 16, 4};   // cps={64,64,64,128,512,2048}
    const int KOFF_[6] = {0, 256, 512, 768, 1792, 5888};
    for (int lvl = 0; lvl < 6; lvl++) {
        int pn     = MS_[lvl];
        int rows   = 16 * pn * pn;
        int tiles  = (rows + 255) / 256;
        int slices = SL_[lvl];
        const float* src = lvl ? zrest : z_enc;

        argmin_kernel<<<tiles * slices, 512, 0, stream>>>(
            lvl == 5 ? zrest : zd_f32, emb_pk, esq, keys + KOFF_[lvl],
            tiles, slices, rows, lvl == 5 ? 1 : 0);
        int pnn = (lvl < 4) ? MS_[lvl + 1] : 0;
        up_kernel<<<NTOT / 4 / 256, 256, 0, stream>>>(
            emb, keys + KOFF_[lvl], src, lvl ? (out + (size_t)(lvl - 1) * NTOT) : out,
            zrest, out + (size_t)lvl * NTOT, zd_f32,
            pn, lvl == 5 ? 1 : 0, lvl == 0 ? 1 : 0, pnn);
    }
}

// Round 24
// 412.582 us; speedup vs baseline: 1.0110x; 1.0110x over previous
//
#include <hip/hip_runtime.h>
#include <hip/hip_bf16.h>

#define NCODES 8192
#define CDIM 128
#define NTOT (16*128*32*32)   // 2097152
#define KTOT 22272            // sum of 256-aligned per-level keys regions

typedef __attribute__((ext_vector_type(8))) short bf16x8;
typedef __attribute__((ext_vector_type(16))) float f32x16;
typedef unsigned long long u64;
typedef unsigned int u32;
typedef unsigned short ushort_t;

__device__ __forceinline__ ushort_t f2bf(float x) {
    u32 u = __float_as_uint(x);
    u32 r = (u + 0x7FFFu + ((u >> 16) & 1u)) >> 16;
    return (ushort_t)r;
}
__device__ __forceinline__ float bf2f(ushort_t h) {
    return __uint_as_float(((u32)h) << 16);
}
__device__ __forceinline__ void gload_lds16(const void* g, void* l) {
    __builtin_amdgcn_global_load_lds(
        (const __attribute__((address_space(1))) unsigned int*)g,
        (__attribute__((address_space(3))) unsigned int*)l, 16, 0, 0);
}

// ---------------- init: emb pack+esq (bid<256) || keys init + lvl0 down -------
__global__ __launch_bounds__(256) void init_kernel(const float* __restrict__ emb,
        const float* __restrict__ z_enc, ushort_t* __restrict__ emb_pk,
        float* __restrict__ esq, float* __restrict__ zd, u64* __restrict__ keys) {
    int bid = blockIdx.x, t = threadIdx.x;
    if (bid < 256) {   // ---- emb pack + esq ----
        __shared__ float sm[32][129];
        int rb = bid;
        int rl = t >> 3, d0 = (t & 7) * 16;
        const float4* s4 = (const float4*)(emb + (size_t)(rb * 32 + rl) * CDIM + d0);
        #pragma unroll
        for (int j = 0; j < 4; j++) {
            float4 v = s4[j];
            sm[rl][d0 + 4*j + 0] = v.x; sm[rl][d0 + 4*j + 1] = v.y;
            sm[rl][d0 + 4*j + 2] = v.z; sm[rl][d0 + 4*j + 3] = v.w;
        }
        __syncthreads();
        {   // esq: 8 threads per code row, 16 dims each
            int r = t >> 3, g = t & 7;
            float s = 0.f;
            #pragma unroll
            for (int k = 0; k < 16; k++) { float x = sm[r][g * 16 + k]; s += x * x; }
            s += __shfl_xor(s, 1, 64);
            s += __shfl_xor(s, 2, 64);
            s += __shfl_xor(s, 4, 64);
            if (g == 0) esq[rb * 32 + r] = s;
        }
        #pragma unroll
        for (int k = 0; k < 2; k++) {
            int s = t + 256 * k;
            int c = s >> 6, l = s & 63;
            int r = l & 31, dbase = c * 16 + (l >> 5) * 8;
            bf16x8 vh, vl;
            #pragma unroll
            for (int e = 0; e < 8; e++) {
                float x = sm[r][dbase + e];
                ushort_t hh = f2bf(x);
                vh[e] = (short)hh;
                vl[e] = (short)f2bf(x - bf2f(hh));
            }
            size_t base = ((size_t)(rb * 8 + c) * 2) * 512 + (size_t)l * 8;
            *(bf16x8*)(emb_pk + base)       = vh;
            *(bf16x8*)(emb_pk + base + 512) = vl;
        }
    } else {           // ---- keys init + lvl0 area downsample ----
        int gi = (bid - 256) * 256 + t;
        if (gi < KTOT) keys[gi] = ~0ull;
        int item = gi >> 6;
        int wi   = gi & 63;
        int row = item >> 7, dim = item & 127;   // row in [0,16)
        const float* sp = z_enc + (((size_t)row * CDIM + dim) * 32) * 32;
        float s = 0.f;
        #pragma unroll
        for (int k = 0; k < 16; k++) {
            int flat = wi * 16 + k;
            s += sp[(flat >> 5) * 32 + (flat & 31)];
        }
        #pragma unroll
        for (int d = 32; d; d >>= 1) s += __shfl_xor(s, d, 64);
        if (wi == 0) zd[(size_t)row * CDIM + dim] = s * (1.0f / 1024.0f);
    }
}

// ---------------- MFMA argmin (fused A-pack): 8 waves x 32 rows --------------
// cstep: 128 when cps>128 (L4/L5: >=4 steps amortize the fixed per-step cost),
// 64 when cps==128 (L3: keeps steps=2 double-buffer overlap -- R23 showed
// steps=1 serializes the 64KB stage), cps otherwise. 2x64KB LDS, ~88 VGPR.
__global__ __launch_bounds__(512) void argmin_kernel(
        const float* __restrict__ zsrc, const ushort_t* __restrict__ bpk,
        const float* __restrict__ esq, u64* __restrict__ keys,
        int tiles, int slices, int nrows, int bchw) {
    __shared__ ushort_t lds[2][32768];   // 2 x 64 KB
    __shared__ float es_lds[2048];

    int cps   = NCODES / slices;
    int cstep = cps > 128 ? 128 : (cps == 128 ? 64 : cps);
    int ngr   = cstep >> 5;              // groups of 32 codes (2 or 4)
    int steps = cps / cstep;
    int stepB = cstep << 9;              // bytes per step block
    int bid = blockIdx.x;
    int tile  = bid / slices;
    int slice = bid % slices;
    int code0 = slice * cps;
    int tid = threadIdx.x, wv = tid >> 6, l = tid & 63, l31 = l & 31, lh = l >> 5;

    // A fragments (32 rows/wave): load f32, scale -2, hi/lo split in regs
    int rb = tile * 8 + wv;
    bf16x8 a_h[8], a_l[8];
    if (bchw) {
        int b = rb >> 5, h = rb & 31;
        const float* zr = zsrc + (size_t)b * 131072 + h * 32 + l31;
        #pragma unroll
        for (int c = 0; c < 8; c++) {
            #pragma unroll
            for (int e = 0; e < 8; e++) {
                int d = c * 16 + lh * 8 + e;
                float x = -2.0f * zr[(size_t)d * 1024];
                ushort_t hh = f2bf(x);
                a_h[c][e] = (short)hh;
                a_l[c][e] = (short)f2bf(x - bf2f(hh));
            }
        }
    } else {
        int row = rb * 32 + l31;
        if (row > nrows - 1) row = nrows - 1;
        const float* zr = zsrc + (size_t)row * CDIM + lh * 8;
        #pragma unroll
        for (int c = 0; c < 8; c++) {
            float4 f0 = *(const float4*)(zr + c * 16);
            float4 f1 = *(const float4*)(zr + c * 16 + 4);
            float xs[8] = {f0.x, f0.y, f0.z, f0.w, f1.x, f1.y, f1.z, f1.w};
            #pragma unroll
            for (int e = 0; e < 8; e++) {
                float x = -2.0f * xs[e];
                ushort_t hh = f2bf(x);
                a_h[c][e] = (short)hh;
                a_l[c][e] = (short)f2bf(x - bf2f(hh));
            }
        }
    }
    float ev0 = 0.f, ev1 = 0.f, ev2 = 0.f, ev3 = 0.f;
    if (tid < cps)        ev0 = esq[code0 + tid];
    if (512  + tid < cps) ev1 = esq[code0 + 512 + tid];
    if (1024 + tid < cps) ev2 = esq[code0 + 1024 + tid];
    if (1536 + tid < cps) ev3 = esq[code0 + 1536 + tid];
    __builtin_amdgcn_sched_barrier(0);   // pin: A+esq before staging

    const char* bbase = (const char*)bpk + (size_t)code0 * 512;
    int wb = wv * ngr * 2048;            // this wave's byte offset in a step block
    {   // prologue: stage step 0 into buf 0 (2*ngr x 1KB per wave)
        const char* g0 = bbase + (size_t)wb + (size_t)l * 16;
        ushort_t* d0 = &lds[0][wb >> 1];
        for (int q = 0; q < 2 * ngr; q++)
            gload_lds16(g0 + q * 1024, d0 + q * 512);
    }
    __builtin_amdgcn_sched_barrier(0);
    if (tid < cps)        es_lds[tid] = ev0;
    if (512  + tid < cps) es_lds[512 + tid] = ev1;
    if (1024 + tid < cps) es_lds[1024 + tid] = ev2;
    if (1536 + tid < cps) es_lds[1536 + tid] = ev3;
    asm volatile("s_waitcnt lgkmcnt(0)" ::: "memory");

    float best[16];
    int   bidx[16];
    #pragma unroll
    for (int r = 0; r < 16; r++) { best[r] = 1e38f; bidx[r] = 0; }

    for (int t = 0; t < steps; ++t) {
        asm volatile("s_waitcnt vmcnt(0)" ::: "memory");  // own stage(t) landed
        __builtin_amdgcn_s_barrier();    // buf[t&1] staged; buf[(t+1)&1] free
        if (t + 1 < steps) {             // stage t+1
            const char* g = bbase + (size_t)(t + 1) * stepB
                          + (size_t)wb + (size_t)l * 16;
            ushort_t* d = &lds[(t + 1) & 1][wb >> 1];
            for (int q = 0; q < 2 * ngr; q++)
                gload_lds16(g + q * 1024, d + q * 512);
        }
        const ushort_t* lpb = &lds[t & 1][0] + l * 8;
        __builtin_amdgcn_s_setprio(1);
        for (int gp = 0; gp < (ngr >> 1); gp++) {
            float es0 = es_lds[t * cstep + (gp << 6) + l31];
            float es1 = es_lds[t * cstep + (gp << 6) + 32 + l31];
            f32x16 acc0, acc1;
            #pragma unroll
            for (int r = 0; r < 16; r++) { acc0[r] = es0; acc1[r] = es1; }
            const ushort_t* lp = lpb + gp * 16384;
            #pragma unroll
            for (int c = 0; c < 8; c++) {
                bf16x8 g0h = *(const bf16x8*)(lp + (2 * c) * 512);
                bf16x8 g0l = *(const bf16x8*)(lp + (2 * c + 1) * 512);
                bf16x8 g1h = *(const bf16x8*)(lp + 8192 + (2 * c) * 512);
                bf16x8 g1l = *(const bf16x8*)(lp + 8192 + (2 * c + 1) * 512);
                acc0 = __builtin_amdgcn_mfma_f32_32x32x16_bf16(a_h[c], g0h, acc0, 0, 0, 0);
                acc1 = __builtin_amdgcn_mfma_f32_32x32x16_bf16(a_h[c], g1h, acc1, 0, 0, 0);
                acc0 = __builtin_amdgcn_mfma_f32_32x32x16_bf16(a_h[c], g0l, acc0, 0, 0, 0);
                acc1 = __builtin_amdgcn_mfma_f32_32x32x16_bf16(a_h[c], g1l, acc1, 0, 0, 0);
                acc0 = __builtin_amdgcn_mfma_f32_32x32x16_bf16(a_l[c], g0h, acc0, 0, 0, 0);
                acc1 = __builtin_amdgcn_mfma_f32_32x32x16_bf16(a_l[c], g1h, acc1, 0, 0, 0);
            }
            int code = code0 + t * cstep + (gp << 6) + l31;
            #pragma unroll
            for (int r = 0; r < 16; r++) {
                float s0 = acc0[r], s1 = acc1[r];
                float m  = fminf(s0, s1);
                int   ci = (s0 <= s1) ? code : code + 32;   // tie -> lower index
                bool lt = m < best[r];
                best[r] = lt ? m : best[r];
                bidx[r] = lt ? ci : bidx[r];
            }
        }
        __builtin_amdgcn_s_setprio(0);
    }

    #pragma unroll
    for (int r = 0; r < 16; r++) {
        u32 fb = __float_as_uint(best[r]);
        fb = (fb & 0x80000000u) ? ~fb : (fb | 0x80000000u);
        u64 key = ((u64)fb << 32) | (u32)bidx[r];
        #pragma unroll
        for (int d = 1; d < 32; d <<= 1) {
            u64 o = __shfl_xor(key, d, 64);
            key = (o < key) ? o : key;
        }
        if (l31 == 0) {
            int rw = tile * 256 + wv * 32 + (r & 3) + 8 * (r >> 2) + 4 * lh;
            atomicMin(&keys[rw], key);
        }
    }
}

// ---------------- bicubic weight (a = -0.75) ----------------
__device__ __forceinline__ float cubicw(float t) {
    float t2 = t * t;
    if (t <= 1.0f) return (1.25f * t - 2.25f) * t2 + 1.0f;
    return -0.75f * (((t - 5.0f) * t + 8.0f) * t - 4.0f);
}

// ---------------- upsample + residual update + output + FUSED downsample ----------
__global__ __launch_bounds__(256) void up_kernel(
        const float* __restrict__ emb,
        const u64* __restrict__ keys,
        const float* __restrict__ src,   // z_enc (lvl0) or zrest
        const float* __restrict__ prev,  // out[lvl-1] (unused if first)
        float* __restrict__ zrest,
        float* __restrict__ out,
        float* __restrict__ zd_next,     // next level's zd (if pnn > 0)
        int pn, int last, int first, int pnn) {
    __shared__ float wtab[32][4];
    __shared__ int   itab[32][4];
    __shared__ float smp[512];
    int tid = threadIdx.x;
    if (!last && tid < 128) {
        int pos = tid >> 2, tap = tid & 3;
        float s  = (float)pn * (1.0f / 32.0f);
        float x  = ((float)pos + 0.5f) * s - 0.5f;
        float x0 = floorf(x);
        float t  = x - x0;
        int   off = tap - 1;
        float w  = cubicw(fabsf((float)off - t));
        int   jj = (int)x0 + off;
        jj = min(max(jj, 0), pn - 1);
        wtab[pos][tap] = w;
        itab[pos][tap] = jj;
    }
    __syncthreads();

    int t  = blockIdx.x * 256 + tid;
    int w4 = (t & 7) << 2;
    int h  = (t >> 3) & 31;
    int c  = (t >> 8) & 127;
    int b  = t >> 15;
    size_t i = (((size_t)b * CDIM + c) * 32 + h) * 32 + w4;

    float zu[4];
    if (last) {
        int kb = (b << 10) + (h << 5) + w4;
        #pragma unroll
        for (int j = 0; j < 4; j++) {
            int tok = (int)(keys[kb + j] & 0xFFFFFFFFull);
            zu[j] = emb[(size_t)tok * CDIM + c];
        }
    } else {
        int base = b * pn * pn;
        #pragma unroll
        for (int j = 0; j < 4; j++) zu[j] = 0.f;
        #pragma unroll
        for (int u = 0; u < 4; u++) {
            float whu = wtab[h][u];
            int   ih  = itab[h][u] * pn;
            #pragma unroll
            for (int j = 0; j < 4; j++) {
                float acc = 0.f;
                #pragma unroll
                for (int v = 0; v < 4; v++) {
                    int tok = (int)(keys[base + ih + itab[w4 + j][v]] & 0xFFFFFFFFull);
                    acc += wtab[w4 + j][v] * emb[(size_t)tok * CDIM + c];
                }
                zu[j] += whu * acc;
            }
        }
    }
    float4 sv = *(const float4*)(src + i);
    float4 pv = {0.f, 0.f, 0.f, 0.f};
    if (!first) pv = *(const float4*)(prev + i);
    float4 ov, rv;
    ov.x = pv.x + zu[0]; ov.y = pv.y + zu[1]; ov.z = pv.z + zu[2]; ov.w = pv.w + zu[3];
    rv.x = sv.x - zu[0]; rv.y = sv.y - zu[1]; rv.z = sv.z - zu[2]; rv.w = sv.w - zu[3];
    *(float4*)(out + i)   = ov;
    *(float4*)(zrest + i) = rv;

    if (pnn) {   // fused area-downsample of rv for next level
        int f = 32 / pnn;
        if (f >= 4) {
            smp[h * 8 + (w4 >> 2)] = (rv.x + rv.y) + (rv.z + rv.w);
        } else {  // f == 2
            smp[h * 16 + (w4 >> 1)]     = rv.x + rv.y;
            smp[h * 16 + (w4 >> 1) + 1] = rv.z + rv.w;
        }
        __syncthreads();
        int W = pnn * pnn;
        if (tid < W) {
            int lb = __builtin_ctz(pnn);
            int ph = tid >> lb, pw = tid & (pnn - 1);
            float s = 0.f;
            if (f >= 4) {
                int cg = f >> 2;
                for (int u = 0; u < f; u++)
                    for (int v = 0; v < cg; v++)
                        s += smp[(ph * f + u) * 8 + pw * cg + v];
            } else {
                s = smp[(2 * ph) * 16 + pw] + smp[(2 * ph + 1) * 16 + pw];
            }
            int b2 = blockIdx.x >> 7, c2 = blockIdx.x & 127;
            int row = (b2 * pnn + ph) * pnn + pw;
            zd_next[(size_t)row * CDIM + c2] = s * (1.0f / (float)(f * f));
        }
    }
}

extern "C" void kernel_launch(void* const* d_in, const int* in_sizes, int n_in,
                              void* d_out, int out_size, void* d_ws, size_t ws_size,
                              hipStream_t stream) {
    const float* z_enc = (const float*)d_in[0];
    const float* emb   = (const float*)d_in[1];
    float* out = (float*)d_out;
    float* ws  = (float*)d_ws;

    // ws layout (float offsets)
    float*    zrest  = ws;                                // 2,097,152
    float*    zd_f32 = ws + 2097152;                      // 2,097,152
    ushort_t* emb_pk = (ushort_t*)(ws + 4194304);         // 2,097,152 ushort
    float*    esq    = ws + 5242880;                      // 8192
    u64*      keys   = (u64*)(ws + 5251072);              // KTOT u64

    init_kernel<<<768, 256, 0, stream>>>(emb, z_enc, emb_pk, esq, zd_f32, keys);

    const int MS_[6]   = {1, 2, 4, 8, 16, 32};
    const int SL_[6]   = {128, 128, 128, 64, 16, 4};   // cps={64,64,64,128,512,2048}
    const int KOFF_[6] = {0, 256, 512, 768, 1792, 5888};
    for (int lvl = 0; lvl < 6; lvl++) {
        int pn     = MS_[lvl];
        int rows   = 16 * pn * pn;
        int tiles  = (rows + 255) / 256;
        int slices = SL_[lvl];
        const float* src = lvl ? zrest : z_enc;

        argmin_kernel<<<tiles * slices, 512, 0, stream>>>(
            lvl == 5 ? zrest : zd_f32, emb_pk, esq, keys + KOFF_[lvl],
            tiles, slices, rows, lvl == 5 ? 1 : 0);
        int pnn = (lvl < 4) ? MS_[lvl + 1] : 0;
        up_kernel<<<NTOT / 4 / 256, 256, 0, stream>>>(
            emb, keys + KOFF_[lvl], src, lvl ? (out + (size_t)(lvl - 1) * NTOT) : out,
            zrest, out + (size_t)lvl * NTOT, zd_f32,
            pn, lvl == 5 ? 1 : 0, lvl == 0 ? 1 : 0, pnn);
    }
}